// Round 4
// baseline (266.872 us; speedup 1.0000x reference)
//
#include <hip/hip_runtime.h>
#include <math.h>

namespace {
constexpr int Bn = 4, Rn = 16384, Sn = 128;
constexpr int NRAY = Bn * Rn;          // 65536 rays
constexpr int SI   = Sn - 1;           // 127 intervals
constexpr int RPW  = 4;                // rays per wave
// Output layout: tuple concatenated flat in return order
constexpr size_t OFF_RGB   = 0;                                  // [B,R,3]
constexpr size_t OFF_DEPTH = OFF_RGB   + (size_t)NRAY * 3;       // [B,R,1]
constexpr size_t OFF_W     = OFF_DEPTH + (size_t)NRAY;           // [B,R,SI,1]
constexpr size_t OFF_WALL  = OFF_W     + (size_t)NRAY * SI;      // [B,R,SI,1]
constexpr size_t OFF_ALPHA = OFF_WALL  + (size_t)NRAY * SI;      // [B,R,SI,1]
constexpr size_t OFF_DMID  = OFF_ALPHA + (size_t)NRAY * SI;      // [B,R,SI,1]
constexpr float  EPSF      = 1e-10f;
}

// ---- DPP helpers (pure-VALU cross-lane; no LDS/bpermute) ----
// ctrl encodings (gfx9/CDNA): row_shr:N = 0x110|N, wave_shl:1 = 0x130,
// wave_shr:1 = 0x138, row_bcast:15 = 0x142, row_bcast:31 = 0x143.
// ROW_MASK: lanes in masked-out rows return `oldv` (write suppressed).
template<int CTRL, int ROW_MASK, bool BC>
__device__ __forceinline__ float dpp_mov(float oldv, float src) {
    return __int_as_float(__builtin_amdgcn_update_dpp(
        __float_as_int(oldv), __float_as_int(src), CTRL, ROW_MASK, 0xF, BC));
}

// 64-lane inclusive prefix PRODUCT (GPUOpen scan; bcast row masks REQUIRED:
// bcast15 -> rows 1,3 only (0xa), bcast31 -> rows 2,3 only (0xc)).
__device__ __forceinline__ float wave_prefix_prod(float s) {
    s *= dpp_mov<0x111, 0xF, false>(1.0f, s);   // row_shr:1
    s *= dpp_mov<0x112, 0xF, false>(1.0f, s);   // row_shr:2
    s *= dpp_mov<0x114, 0xF, false>(1.0f, s);   // row_shr:4
    s *= dpp_mov<0x118, 0xF, false>(1.0f, s);   // row_shr:8
    s *= dpp_mov<0x142, 0xa, false>(1.0f, s);   // row_bcast:15 -> rows 1,3
    s *= dpp_mov<0x143, 0xc, false>(1.0f, s);   // row_bcast:31 -> rows 2,3
    return s;
}

// 64-lane sum; lane 63 holds the total afterwards.
__device__ __forceinline__ float wave_sum_last(float x) {
    x += dpp_mov<0x111, 0xF, true>(0.0f, x);
    x += dpp_mov<0x112, 0xF, true>(0.0f, x);
    x += dpp_mov<0x114, 0xF, true>(0.0f, x);
    x += dpp_mov<0x118, 0xF, true>(0.0f, x);
    x += dpp_mov<0x142, 0xa, true>(0.0f, x);
    x += dpp_mov<0x143, 0xc, true>(0.0f, x);
    return x;
}

// One wave per RPW consecutive rays; within a ray, lane i owns intervals 2i, 2i+1.
// All global loads for the RPW rays are issued before any compute: 20 loads in
// flight per wave (4x the MLP of the 1-ray version), and the 4 rays' dependent
// trans/DPP chains interleave to hide each other's latency.
__global__ __launch_bounds__(256) void raymarch_kernel(
    const float* __restrict__ colors,
    const float* __restrict__ dlog,
    const float* __restrict__ depths,
    float* __restrict__ out)
{
    const int wid  = (blockIdx.x * 256 + threadIdx.x) >> 6;   // wave id
    const int lane = threadIdx.x & 63;
    const int ray0 = wid * RPW;

    // ---- hoisted loads for all RPW rays (issue back-to-back) ----
    float2 d[RPW], g[RPW], c0[RPW], c1[RPW], c2[RPW];
    #pragma unroll
    for (int r = 0; r < RPW; ++r) {
        const int ray = ray0 + r;
        const float2* dp = reinterpret_cast<const float2*>(depths) + (size_t)ray * (Sn / 2);
        const float2* gp = reinterpret_cast<const float2*>(dlog)   + (size_t)ray * (Sn / 2);
        const float2* cp = reinterpret_cast<const float2*>(colors) + (size_t)ray * (Sn * 3 / 2);
        d[r]  = dp[lane];
        g[r]  = gp[lane];
        c0[r] = cp[lane * 3 + 0];
        c1[r] = cp[lane * 3 + 1];
        c2[r] = cp[lane * 3 + 2];
    }

    const bool valid1 = (lane < 63);   // interval 2*63+1 does not exist

    #pragma unroll
    for (int r = 0; r < RPW; ++r) {
        const int ray = ray0 + r;

        // sample 2i+2 lives in lane i+1's first slots: wave_shl:1.
        float d2  = dpp_mov<0x130, 0xF, false>(d[r].x,  d[r].x);
        float g2  = dpp_mov<0x130, 0xF, false>(g[r].x,  g[r].x);
        float cnx = dpp_mov<0x130, 0xF, false>(c0[r].x, c0[r].x);
        float cny = dpp_mov<0x130, 0xF, false>(c0[r].y, c0[r].y);
        float cnz = dpp_mov<0x130, 0xF, false>(c1[r].x, c1[r].x);

        // interval j0 = 2i : samples (2i, 2i+1)
        float delta0 = d[r].y - d[r].x;
        float dm0    = 0.5f * (d[r].x + d[r].y);
        float x0     = 0.5f * (g[r].x + g[r].y) - 1.0f;
        float cm0x   = 0.5f * (c0[r].x + c1[r].y);
        float cm0y   = 0.5f * (c0[r].y + c2[r].x);
        float cm0z   = 0.5f * (c1[r].x + c2[r].y);

        // interval j1 = 2i+1 : samples (2i+1, 2i+2) — safe values when invalid
        float delta1 = valid1 ? (d2 - d[r].y)         : 0.0f;
        float dm1    = valid1 ? 0.5f * (d[r].y + d2)  : 0.0f;
        float x1     = valid1 ? (0.5f * (g[r].y + g2) - 1.0f) : 0.0f;
        float cm1x   = valid1 ? 0.5f * (c1[r].y + cnx) : 0.0f;
        float cm1y   = valid1 ? 0.5f * (c2[r].x + cny) : 0.0f;
        float cm1z   = valid1 ? 0.5f * (c2[r].y + cnz) : 0.0f;

        // alpha = 1 - exp(-softplus(x)*delta) = 1 - 2^(-delta * log2(1+e^x))
        float l0 = __log2f(1.0f + __expf(x0));
        float l1 = __log2f(1.0f + __expf(x1));
        l0 = fminf(l0, 1e30f);             // guard inf*0 -> NaN when delta==0
        l1 = fminf(l1, 1e30f);
        float E0 = exp2f(-delta0 * l0);    // = 1 - alpha0
        float E1 = exp2f(-delta1 * l1);
        float alpha0 = 1.0f - E0;
        float alpha1 = 1.0f - E1;          // == 0 for lane 63 (delta1=0)
        float t0 = E0 + EPSF;
        float t1 = valid1 ? (E1 + EPSF) : 1.0f;

        // wave-wide inclusive prefix product (cumprod), all DPP.
        float s  = wave_prefix_prod(t0 * t1);
        float T0 = dpp_mov<0x138, 0xF, false>(1.0f, s);   // exclusive; lane0 -> 1.0
        float T1 = T0 * t0;

        float w0 = (alpha0 + EPSF) * T0;
        float w1 = valid1 ? (alpha1 + EPSF) * T1 : 0.0f;

        // per-interval outputs. ray = 4*wid + r, so ray parity == r parity at
        // compile time: even r -> float index OFF + 127*ray + 2*lane is even ->
        // 8B-aligned -> safe dwordx2 stores (lanes 0..62). Odd r -> dword pairs.
        const size_t base = (size_t)ray * SI + 2 * lane;
        if constexpr (true) {
            if ((r & 1) == 0) {
                if (valid1) {
                    *reinterpret_cast<float2*>(out + OFF_W     + base) = make_float2(w0, w1);
                    *reinterpret_cast<float2*>(out + OFF_WALL  + base) = make_float2(w0, w1);
                    *reinterpret_cast<float2*>(out + OFF_ALPHA + base) = make_float2(alpha0, alpha1);
                    *reinterpret_cast<float2*>(out + OFF_DMID  + base) = make_float2(dm0, dm1);
                } else {
                    out[OFF_W     + base] = w0;
                    out[OFF_WALL  + base] = w0;
                    out[OFF_ALPHA + base] = alpha0;
                    out[OFF_DMID  + base] = dm0;
                }
            } else {
                out[OFF_W     + base] = w0;
                out[OFF_WALL  + base] = w0;
                out[OFF_ALPHA + base] = alpha0;
                out[OFF_DMID  + base] = dm0;
                if (valid1) {
                    out[OFF_W     + base + 1] = w1;
                    out[OFF_WALL  + base + 1] = w1;
                    out[OFF_ALPHA + base + 1] = alpha1;
                    out[OFF_DMID  + base + 1] = dm1;
                }
            }
        }

        // composite reductions over the wave — totals land on lane 63
        float wsum = wave_sum_last(w0 + w1);
        float rx   = wave_sum_last(w0 * cm0x + w1 * cm1x);
        float ry   = wave_sum_last(w0 * cm0y + w1 * cm1y);
        float rz   = wave_sum_last(w0 * cm0z + w1 * cm1z);
        float dsum = wave_sum_last(w0 * dm0  + w1 * dm1);

        if (lane == 63) {
            float cd = dsum / (EPSF + wsum);
            if (isnan(cd)) cd = 100.0f;              // nan_to_num(nan=MAX_DEPTH)
            cd = fminf(fmaxf(cd, 0.1f), 100.0f);     // clip; also maps ±inf
            out[OFF_RGB + (size_t)ray * 3 + 0] = rx * 2.0f - 1.0f;
            out[OFF_RGB + (size_t)ray * 3 + 1] = ry * 2.0f - 1.0f;
            out[OFF_RGB + (size_t)ray * 3 + 2] = rz * 2.0f - 1.0f;
            out[OFF_DEPTH + ray] = cd;
        }
    }
}

extern "C" void kernel_launch(void* const* d_in, const int* in_sizes, int n_in,
                              void* d_out, int out_size, void* d_ws, size_t ws_size,
                              hipStream_t stream) {
    const float* colors = (const float*)d_in[0];
    const float* dlog   = (const float*)d_in[1];
    const float* depths = (const float*)d_in[2];
    float* out = (float*)d_out;

    dim3 grid(NRAY / (4 * RPW));   // 4 waves per block, RPW rays per wave
    dim3 block(256);
    hipLaunchKernelGGL(raymarch_kernel, grid, block, 0, stream, colors, dlog, depths, out);
}

// Round 5
// 265.982 us; speedup vs baseline: 1.0033x; 1.0033x over previous
//
#include <hip/hip_runtime.h>
#include <math.h>

namespace {
constexpr int Bn = 4, Rn = 16384, Sn = 128;
constexpr int NRAY = Bn * Rn;          // 65536 rays
constexpr int SI   = Sn - 1;           // 127 intervals
constexpr int RPW  = 4;                // rays per wave
// Output layout: tuple concatenated flat in return order
constexpr size_t OFF_RGB   = 0;                                  // [B,R,3]
constexpr size_t OFF_DEPTH = OFF_RGB   + (size_t)NRAY * 3;       // [B,R,1]
constexpr size_t OFF_W     = OFF_DEPTH + (size_t)NRAY;           // [B,R,SI,1]
constexpr size_t OFF_WALL  = OFF_W     + (size_t)NRAY * SI;      // [B,R,SI,1]
constexpr size_t OFF_ALPHA = OFF_WALL  + (size_t)NRAY * SI;      // [B,R,SI,1]
constexpr size_t OFF_DMID  = OFF_ALPHA + (size_t)NRAY * SI;      // [B,R,SI,1]
constexpr float  EPSF      = 1e-10f;
}

// ---- DPP helpers (pure-VALU cross-lane; no LDS/bpermute) ----
// ctrl encodings (gfx9/CDNA): row_shr:N = 0x110|N, wave_shl:1 = 0x130,
// wave_shr:1 = 0x138, row_bcast:15 = 0x142, row_bcast:31 = 0x143.
// ROW_MASK: lanes in masked-out rows return `oldv` (write suppressed).
template<int CTRL, int ROW_MASK, bool BC>
__device__ __forceinline__ float dpp_mov(float oldv, float src) {
    return __int_as_float(__builtin_amdgcn_update_dpp(
        __float_as_int(oldv), __float_as_int(src), CTRL, ROW_MASK, 0xF, BC));
}

// 64-lane inclusive prefix PRODUCT (GPUOpen scan; bcast row masks REQUIRED:
// bcast15 -> rows 1,3 only (0xa), bcast31 -> rows 2,3 only (0xc)).
__device__ __forceinline__ float wave_prefix_prod(float s) {
    s *= dpp_mov<0x111, 0xF, false>(1.0f, s);   // row_shr:1
    s *= dpp_mov<0x112, 0xF, false>(1.0f, s);   // row_shr:2
    s *= dpp_mov<0x114, 0xF, false>(1.0f, s);   // row_shr:4
    s *= dpp_mov<0x118, 0xF, false>(1.0f, s);   // row_shr:8
    s *= dpp_mov<0x142, 0xa, false>(1.0f, s);   // row_bcast:15 -> rows 1,3
    s *= dpp_mov<0x143, 0xc, false>(1.0f, s);   // row_bcast:31 -> rows 2,3
    return s;
}

// 64-lane sum; lane 63 holds the total afterwards.
__device__ __forceinline__ float wave_sum_last(float x) {
    x += dpp_mov<0x111, 0xF, true>(0.0f, x);
    x += dpp_mov<0x112, 0xF, true>(0.0f, x);
    x += dpp_mov<0x114, 0xF, true>(0.0f, x);
    x += dpp_mov<0x118, 0xF, true>(0.0f, x);
    x += dpp_mov<0x142, 0xa, true>(0.0f, x);
    x += dpp_mov<0x143, 0xc, true>(0.0f, x);
    return x;
}

// One wave per RPW consecutive rays; within a ray, lane i owns intervals 2i, 2i+1.
// All 20 global loads are issued back-to-back and PINNED there by a
// sched_barrier(0): round 4 showed the machine scheduler otherwise sinks the
// loads into the compute loop (VGPR_Count fell to 32), destroying the MLP.
__global__ __launch_bounds__(256) void raymarch_kernel(
    const float* __restrict__ colors,
    const float* __restrict__ dlog,
    const float* __restrict__ depths,
    float* __restrict__ out)
{
    const int wid  = (blockIdx.x * 256 + threadIdx.x) >> 6;   // wave id
    const int lane = threadIdx.x & 63;
    const int ray0 = wid * RPW;

    // ---- hoisted loads for all RPW rays (issued back-to-back) ----
    float2 d[RPW], g[RPW], c0[RPW], c1[RPW], c2[RPW];
    #pragma unroll
    for (int r = 0; r < RPW; ++r) {
        const int ray = ray0 + r;
        const float2* dp = reinterpret_cast<const float2*>(depths) + (size_t)ray * (Sn / 2);
        const float2* gp = reinterpret_cast<const float2*>(dlog)   + (size_t)ray * (Sn / 2);
        const float2* cp = reinterpret_cast<const float2*>(colors) + (size_t)ray * (Sn * 3 / 2);
        d[r]  = dp[lane];
        g[r]  = gp[lane];
        c0[r] = cp[lane * 3 + 0];
        c1[r] = cp[lane * 3 + 1];
        c2[r] = cp[lane * 3 + 2];
    }
    // Hard scheduling fence: nothing (including the loads above) may cross.
    // This keeps all 20 global_load_dwordx2 in flight before any compute.
    __builtin_amdgcn_sched_barrier(0);

    const bool valid1 = (lane < 63);   // interval 2*63+1 does not exist

    #pragma unroll
    for (int r = 0; r < RPW; ++r) {
        const int ray = ray0 + r;

        // sample 2i+2 lives in lane i+1's first slots: wave_shl:1.
        float d2  = dpp_mov<0x130, 0xF, false>(d[r].x,  d[r].x);
        float g2  = dpp_mov<0x130, 0xF, false>(g[r].x,  g[r].x);
        float cnx = dpp_mov<0x130, 0xF, false>(c0[r].x, c0[r].x);
        float cny = dpp_mov<0x130, 0xF, false>(c0[r].y, c0[r].y);
        float cnz = dpp_mov<0x130, 0xF, false>(c1[r].x, c1[r].x);

        // interval j0 = 2i : samples (2i, 2i+1)
        float delta0 = d[r].y - d[r].x;
        float dm0    = 0.5f * (d[r].x + d[r].y);
        float x0     = 0.5f * (g[r].x + g[r].y) - 1.0f;
        float cm0x   = 0.5f * (c0[r].x + c1[r].y);
        float cm0y   = 0.5f * (c0[r].y + c2[r].x);
        float cm0z   = 0.5f * (c1[r].x + c2[r].y);

        // interval j1 = 2i+1 : samples (2i+1, 2i+2) — safe values when invalid
        float delta1 = valid1 ? (d2 - d[r].y)         : 0.0f;
        float dm1    = valid1 ? 0.5f * (d[r].y + d2)  : 0.0f;
        float x1     = valid1 ? (0.5f * (g[r].y + g2) - 1.0f) : 0.0f;
        float cm1x   = valid1 ? 0.5f * (c1[r].y + cnx) : 0.0f;
        float cm1y   = valid1 ? 0.5f * (c2[r].x + cny) : 0.0f;
        float cm1z   = valid1 ? 0.5f * (c2[r].y + cnz) : 0.0f;

        // alpha = 1 - exp(-softplus(x)*delta) = 1 - 2^(-delta * log2(1+e^x))
        float l0 = __log2f(1.0f + __expf(x0));
        float l1 = __log2f(1.0f + __expf(x1));
        l0 = fminf(l0, 1e30f);             // guard inf*0 -> NaN when delta==0
        l1 = fminf(l1, 1e30f);
        float E0 = exp2f(-delta0 * l0);    // = 1 - alpha0
        float E1 = exp2f(-delta1 * l1);
        float alpha0 = 1.0f - E0;
        float alpha1 = 1.0f - E1;          // == 0 for lane 63 (delta1=0)
        float t0 = E0 + EPSF;
        float t1 = valid1 ? (E1 + EPSF) : 1.0f;

        // wave-wide inclusive prefix product (cumprod), all DPP.
        float s  = wave_prefix_prod(t0 * t1);
        float T0 = dpp_mov<0x138, 0xF, false>(1.0f, s);   // exclusive; lane0 -> 1.0
        float T1 = T0 * t0;

        float w0 = (alpha0 + EPSF) * T0;
        float w1 = valid1 ? (alpha1 + EPSF) * T1 : 0.0f;

        // per-interval outputs. ray = 4*wid + r, so ray parity == r parity at
        // compile time: even r -> float index OFF + 127*ray + 2*lane is even ->
        // 8B-aligned -> safe dwordx2 stores (lanes 0..62). Odd r -> dword pairs.
        const size_t base = (size_t)ray * SI + 2 * lane;
        if ((r & 1) == 0) {
            if (valid1) {
                *reinterpret_cast<float2*>(out + OFF_W     + base) = make_float2(w0, w1);
                *reinterpret_cast<float2*>(out + OFF_WALL  + base) = make_float2(w0, w1);
                *reinterpret_cast<float2*>(out + OFF_ALPHA + base) = make_float2(alpha0, alpha1);
                *reinterpret_cast<float2*>(out + OFF_DMID  + base) = make_float2(dm0, dm1);
            } else {
                out[OFF_W     + base] = w0;
                out[OFF_WALL  + base] = w0;
                out[OFF_ALPHA + base] = alpha0;
                out[OFF_DMID  + base] = dm0;
            }
        } else {
            out[OFF_W     + base] = w0;
            out[OFF_WALL  + base] = w0;
            out[OFF_ALPHA + base] = alpha0;
            out[OFF_DMID  + base] = dm0;
            if (valid1) {
                out[OFF_W     + base + 1] = w1;
                out[OFF_WALL  + base + 1] = w1;
                out[OFF_ALPHA + base + 1] = alpha1;
                out[OFF_DMID  + base + 1] = dm1;
            }
        }

        // composite reductions over the wave — totals land on lane 63
        float wsum = wave_sum_last(w0 + w1);
        float rx   = wave_sum_last(w0 * cm0x + w1 * cm1x);
        float ry   = wave_sum_last(w0 * cm0y + w1 * cm1y);
        float rz   = wave_sum_last(w0 * cm0z + w1 * cm1z);
        float dsum = wave_sum_last(w0 * dm0  + w1 * dm1);

        if (lane == 63) {
            float cd = dsum / (EPSF + wsum);
            if (isnan(cd)) cd = 100.0f;              // nan_to_num(nan=MAX_DEPTH)
            cd = fminf(fmaxf(cd, 0.1f), 100.0f);     // clip; also maps ±inf
            out[OFF_RGB + (size_t)ray * 3 + 0] = rx * 2.0f - 1.0f;
            out[OFF_RGB + (size_t)ray * 3 + 1] = ry * 2.0f - 1.0f;
            out[OFF_RGB + (size_t)ray * 3 + 2] = rz * 2.0f - 1.0f;
            out[OFF_DEPTH + ray] = cd;
        }
    }
}

extern "C" void kernel_launch(void* const* d_in, const int* in_sizes, int n_in,
                              void* d_out, int out_size, void* d_ws, size_t ws_size,
                              hipStream_t stream) {
    const float* colors = (const float*)d_in[0];
    const float* dlog   = (const float*)d_in[1];
    const float* depths = (const float*)d_in[2];
    float* out = (float*)d_out;

    dim3 grid(NRAY / (4 * RPW));   // 4 waves per block, RPW rays per wave
    dim3 block(256);
    hipLaunchKernelGGL(raymarch_kernel, grid, block, 0, stream, colors, dlog, depths, out);
}

// Round 6
// 263.923 us; speedup vs baseline: 1.0112x; 1.0078x over previous
//
#include <hip/hip_runtime.h>
#include <math.h>

namespace {
constexpr int Bn = 4, Rn = 16384, Sn = 128;
constexpr int NRAY = Bn * Rn;          // 65536 rays
constexpr int SI   = Sn - 1;           // 127 intervals
constexpr int RPW  = 4;                // rays per wave
// Output layout: tuple concatenated flat in return order
constexpr size_t OFF_RGB   = 0;                                  // [B,R,3]
constexpr size_t OFF_DEPTH = OFF_RGB   + (size_t)NRAY * 3;       // [B,R,1]
constexpr size_t OFF_W     = OFF_DEPTH + (size_t)NRAY;           // [B,R,SI,1]
constexpr size_t OFF_WALL  = OFF_W     + (size_t)NRAY * SI;      // [B,R,SI,1]
constexpr size_t OFF_ALPHA = OFF_WALL  + (size_t)NRAY * SI;      // [B,R,SI,1]
constexpr size_t OFF_DMID  = OFF_ALPHA + (size_t)NRAY * SI;      // [B,R,SI,1]
constexpr float  EPSF      = 1e-10f;
}

// ---- DPP helpers (pure-VALU cross-lane; no LDS/bpermute) ----
// ctrl encodings (gfx9/CDNA): row_shr:N = 0x110|N, wave_shl:1 = 0x130,
// wave_shr:1 = 0x138, row_bcast:15 = 0x142, row_bcast:31 = 0x143.
// ROW_MASK: lanes in masked-out rows return `oldv` (write suppressed).
template<int CTRL, int ROW_MASK, bool BC>
__device__ __forceinline__ float dpp_mov(float oldv, float src) {
    return __int_as_float(__builtin_amdgcn_update_dpp(
        __float_as_int(oldv), __float_as_int(src), CTRL, ROW_MASK, 0xF, BC));
}

// 64-lane inclusive prefix PRODUCT (GPUOpen scan; bcast row masks REQUIRED:
// bcast15 -> rows 1,3 only (0xa), bcast31 -> rows 2,3 only (0xc)).
__device__ __forceinline__ float wave_prefix_prod(float s) {
    s *= dpp_mov<0x111, 0xF, false>(1.0f, s);   // row_shr:1
    s *= dpp_mov<0x112, 0xF, false>(1.0f, s);   // row_shr:2
    s *= dpp_mov<0x114, 0xF, false>(1.0f, s);   // row_shr:4
    s *= dpp_mov<0x118, 0xF, false>(1.0f, s);   // row_shr:8
    s *= dpp_mov<0x142, 0xa, false>(1.0f, s);   // row_bcast:15 -> rows 1,3
    s *= dpp_mov<0x143, 0xc, false>(1.0f, s);   // row_bcast:31 -> rows 2,3
    return s;
}

// 64-lane sum; lane 63 holds the total afterwards.
__device__ __forceinline__ float wave_sum_last(float x) {
    x += dpp_mov<0x111, 0xF, true>(0.0f, x);
    x += dpp_mov<0x112, 0xF, true>(0.0f, x);
    x += dpp_mov<0x114, 0xF, true>(0.0f, x);
    x += dpp_mov<0x118, 0xF, true>(0.0f, x);
    x += dpp_mov<0x142, 0xa, true>(0.0f, x);
    x += dpp_mov<0x143, 0xc, true>(0.0f, x);
    return x;
}

// One wave per RPW consecutive rays; within a ray, lane i owns intervals 2i, 2i+1.
// The 20 global loads are pinned before compute by a DATA dependence: a single
// asm volatile consumes one component of every load, so no compiler pass can
// sink any load into the compute loop. (R4: plain hoist was sunk, VGPR=32.
// R5: sched_barrier(0) also failed to prevent sinking, VGPR=32. This is the
// only undefeatable pinning mechanism.)
__global__ __launch_bounds__(256) void raymarch_kernel(
    const float* __restrict__ colors,
    const float* __restrict__ dlog,
    const float* __restrict__ depths,
    float* __restrict__ out)
{
    const int wid  = (blockIdx.x * 256 + threadIdx.x) >> 6;   // wave id
    const int lane = threadIdx.x & 63;
    const int ray0 = wid * RPW;

    // ---- hoisted loads for all RPW rays (issued back-to-back) ----
    float2 d[RPW], g[RPW], c0[RPW], c1[RPW], c2[RPW];
    #pragma unroll
    for (int r = 0; r < RPW; ++r) {
        const int ray = ray0 + r;
        const float2* dp = reinterpret_cast<const float2*>(depths) + (size_t)ray * (Sn / 2);
        const float2* gp = reinterpret_cast<const float2*>(dlog)   + (size_t)ray * (Sn / 2);
        const float2* cp = reinterpret_cast<const float2*>(colors) + (size_t)ray * (Sn * 3 / 2);
        d[r]  = dp[lane];
        g[r]  = gp[lane];
        c0[r] = cp[lane * 3 + 0];
        c1[r] = cp[lane * 3 + 1];
        c2[r] = cp[lane * 3 + 2];
    }
    // Data-dependence pin: one component per load instruction. Every load must
    // retire before this point (single s_waitcnt vmcnt(0)), and all 40 payload
    // VGPRs are simultaneously live here -> loads cannot be re-sunk.
    asm volatile(""
        : "+v"(d[0].x),  "+v"(d[1].x),  "+v"(d[2].x),  "+v"(d[3].x),
          "+v"(g[0].x),  "+v"(g[1].x),  "+v"(g[2].x),  "+v"(g[3].x),
          "+v"(c0[0].x), "+v"(c0[1].x), "+v"(c0[2].x), "+v"(c0[3].x),
          "+v"(c1[0].x), "+v"(c1[1].x), "+v"(c1[2].x), "+v"(c1[3].x),
          "+v"(c2[0].x), "+v"(c2[1].x), "+v"(c2[2].x), "+v"(c2[3].x));

    const bool valid1 = (lane < 63);   // interval 2*63+1 does not exist

    #pragma unroll
    for (int r = 0; r < RPW; ++r) {
        const int ray = ray0 + r;

        // sample 2i+2 lives in lane i+1's first slots: wave_shl:1.
        float d2  = dpp_mov<0x130, 0xF, false>(d[r].x,  d[r].x);
        float g2  = dpp_mov<0x130, 0xF, false>(g[r].x,  g[r].x);
        float cnx = dpp_mov<0x130, 0xF, false>(c0[r].x, c0[r].x);
        float cny = dpp_mov<0x130, 0xF, false>(c0[r].y, c0[r].y);
        float cnz = dpp_mov<0x130, 0xF, false>(c1[r].x, c1[r].x);

        // interval j0 = 2i : samples (2i, 2i+1)
        float delta0 = d[r].y - d[r].x;
        float dm0    = 0.5f * (d[r].x + d[r].y);
        float x0     = 0.5f * (g[r].x + g[r].y) - 1.0f;
        float cm0x   = 0.5f * (c0[r].x + c1[r].y);
        float cm0y   = 0.5f * (c0[r].y + c2[r].x);
        float cm0z   = 0.5f * (c1[r].x + c2[r].y);

        // interval j1 = 2i+1 : samples (2i+1, 2i+2) — safe values when invalid
        float delta1 = valid1 ? (d2 - d[r].y)         : 0.0f;
        float dm1    = valid1 ? 0.5f * (d[r].y + d2)  : 0.0f;
        float x1     = valid1 ? (0.5f * (g[r].y + g2) - 1.0f) : 0.0f;
        float cm1x   = valid1 ? 0.5f * (c1[r].y + cnx) : 0.0f;
        float cm1y   = valid1 ? 0.5f * (c2[r].x + cny) : 0.0f;
        float cm1z   = valid1 ? 0.5f * (c2[r].y + cnz) : 0.0f;

        // alpha = 1 - exp(-softplus(x)*delta) = 1 - 2^(-delta * log2(1+e^x))
        float l0 = __log2f(1.0f + __expf(x0));
        float l1 = __log2f(1.0f + __expf(x1));
        l0 = fminf(l0, 1e30f);             // guard inf*0 -> NaN when delta==0
        l1 = fminf(l1, 1e30f);
        float E0 = exp2f(-delta0 * l0);    // = 1 - alpha0
        float E1 = exp2f(-delta1 * l1);
        float alpha0 = 1.0f - E0;
        float alpha1 = 1.0f - E1;          // == 0 for lane 63 (delta1=0)
        float t0 = E0 + EPSF;
        float t1 = valid1 ? (E1 + EPSF) : 1.0f;

        // wave-wide inclusive prefix product (cumprod), all DPP.
        float s  = wave_prefix_prod(t0 * t1);
        float T0 = dpp_mov<0x138, 0xF, false>(1.0f, s);   // exclusive; lane0 -> 1.0
        float T1 = T0 * t0;

        float w0 = (alpha0 + EPSF) * T0;
        float w1 = valid1 ? (alpha1 + EPSF) * T1 : 0.0f;

        // per-interval outputs. ray = 4*wid + r, so ray parity == r parity at
        // compile time: even r -> float index OFF + 127*ray + 2*lane is even ->
        // 8B-aligned -> safe dwordx2 stores (lanes 0..62). Odd r -> dword pairs.
        const size_t base = (size_t)ray * SI + 2 * lane;
        if ((r & 1) == 0) {
            if (valid1) {
                *reinterpret_cast<float2*>(out + OFF_W     + base) = make_float2(w0, w1);
                *reinterpret_cast<float2*>(out + OFF_WALL  + base) = make_float2(w0, w1);
                *reinterpret_cast<float2*>(out + OFF_ALPHA + base) = make_float2(alpha0, alpha1);
                *reinterpret_cast<float2*>(out + OFF_DMID  + base) = make_float2(dm0, dm1);
            } else {
                out[OFF_W     + base] = w0;
                out[OFF_WALL  + base] = w0;
                out[OFF_ALPHA + base] = alpha0;
                out[OFF_DMID  + base] = dm0;
            }
        } else {
            out[OFF_W     + base] = w0;
            out[OFF_WALL  + base] = w0;
            out[OFF_ALPHA + base] = alpha0;
            out[OFF_DMID  + base] = dm0;
            if (valid1) {
                out[OFF_W     + base + 1] = w1;
                out[OFF_WALL  + base + 1] = w1;
                out[OFF_ALPHA + base + 1] = alpha1;
                out[OFF_DMID  + base + 1] = dm1;
            }
        }

        // composite reductions over the wave — totals land on lane 63
        float wsum = wave_sum_last(w0 + w1);
        float rx   = wave_sum_last(w0 * cm0x + w1 * cm1x);
        float ry   = wave_sum_last(w0 * cm0y + w1 * cm1y);
        float rz   = wave_sum_last(w0 * cm0z + w1 * cm1z);
        float dsum = wave_sum_last(w0 * dm0  + w1 * dm1);

        if (lane == 63) {
            float cd = dsum / (EPSF + wsum);
            if (isnan(cd)) cd = 100.0f;              // nan_to_num(nan=MAX_DEPTH)
            cd = fminf(fmaxf(cd, 0.1f), 100.0f);     // clip; also maps ±inf
            out[OFF_RGB + (size_t)ray * 3 + 0] = rx * 2.0f - 1.0f;
            out[OFF_RGB + (size_t)ray * 3 + 1] = ry * 2.0f - 1.0f;
            out[OFF_RGB + (size_t)ray * 3 + 2] = rz * 2.0f - 1.0f;
            out[OFF_DEPTH + ray] = cd;
        }
    }
}

extern "C" void kernel_launch(void* const* d_in, const int* in_sizes, int n_in,
                              void* d_out, int out_size, void* d_ws, size_t ws_size,
                              hipStream_t stream) {
    const float* colors = (const float*)d_in[0];
    const float* dlog   = (const float*)d_in[1];
    const float* depths = (const float*)d_in[2];
    float* out = (float*)d_out;

    dim3 grid(NRAY / (4 * RPW));   // 4 waves per block, RPW rays per wave
    dim3 block(256);
    hipLaunchKernelGGL(raymarch_kernel, grid, block, 0, stream, colors, dlog, depths, out);
}

// Round 7
// 261.009 us; speedup vs baseline: 1.0225x; 1.0112x over previous
//
#include <hip/hip_runtime.h>
#include <math.h>

namespace {
constexpr int Bn = 4, Rn = 16384, Sn = 128;
constexpr int NRAY = Bn * Rn;          // 65536 rays
constexpr int SI   = Sn - 1;           // 127 intervals
constexpr int RPW  = 4;                // rays per wave
// Output layout: tuple concatenated flat in return order
constexpr size_t OFF_RGB   = 0;                                  // [B,R,3]
constexpr size_t OFF_DEPTH = OFF_RGB   + (size_t)NRAY * 3;       // [B,R,1]
constexpr size_t OFF_W     = OFF_DEPTH + (size_t)NRAY;           // [B,R,SI,1]
constexpr size_t OFF_WALL  = OFF_W     + (size_t)NRAY * SI;      // [B,R,SI,1]
constexpr size_t OFF_ALPHA = OFF_WALL  + (size_t)NRAY * SI;      // [B,R,SI,1]
constexpr size_t OFF_DMID  = OFF_ALPHA + (size_t)NRAY * SI;      // [B,R,SI,1]
constexpr float  EPSF      = 1e-10f;
}

// ---- DPP helpers (pure-VALU cross-lane; no LDS/bpermute) ----
// ctrl encodings (gfx9/CDNA): row_shr:N = 0x110|N, wave_shl:1 = 0x130,
// wave_shr:1 = 0x138, row_bcast:15 = 0x142, row_bcast:31 = 0x143.
// ROW_MASK: lanes in masked-out rows return `oldv` (write suppressed).
template<int CTRL, int ROW_MASK, bool BC>
__device__ __forceinline__ float dpp_mov(float oldv, float src) {
    return __int_as_float(__builtin_amdgcn_update_dpp(
        __float_as_int(oldv), __float_as_int(src), CTRL, ROW_MASK, 0xF, BC));
}

// 64-lane inclusive prefix PRODUCT (GPUOpen scan; bcast row masks REQUIRED:
// bcast15 -> rows 1,3 only (0xa), bcast31 -> rows 2,3 only (0xc)).
__device__ __forceinline__ float wave_prefix_prod(float s) {
    s *= dpp_mov<0x111, 0xF, false>(1.0f, s);   // row_shr:1
    s *= dpp_mov<0x112, 0xF, false>(1.0f, s);   // row_shr:2
    s *= dpp_mov<0x114, 0xF, false>(1.0f, s);   // row_shr:4
    s *= dpp_mov<0x118, 0xF, false>(1.0f, s);   // row_shr:8
    s *= dpp_mov<0x142, 0xa, false>(1.0f, s);   // row_bcast:15 -> rows 1,3
    s *= dpp_mov<0x143, 0xc, false>(1.0f, s);   // row_bcast:31 -> rows 2,3
    return s;
}

// 64-lane sum; lane 63 holds the total afterwards.
__device__ __forceinline__ float wave_sum_last(float x) {
    x += dpp_mov<0x111, 0xF, true>(0.0f, x);
    x += dpp_mov<0x112, 0xF, true>(0.0f, x);
    x += dpp_mov<0x114, 0xF, true>(0.0f, x);
    x += dpp_mov<0x118, 0xF, true>(0.0f, x);
    x += dpp_mov<0x142, 0xa, true>(0.0f, x);
    x += dpp_mov<0x143, 0xc, true>(0.0f, x);
    return x;
}

// One wave per RPW consecutive rays; within a ray, lane i owns intervals 2i,2i+1.
//
// Latency-overlap structure (R7):
//   [issue d/g loads][issue color loads]
//   [pin+drain d/g only  -> compiler emits s_waitcnt vmcnt(12), colors in flight]
//   [Phase A: 4 rays of softplus/scan/weights + w/wall/alpha/dmid stores
//             + wsum/dsum reductions  -- hides the 12 color loads' HBM latency]
//   [pin+drain colors (both components -> defeats the .y-split re-sink seen in R6)]
//   [Phase B: color midpoints, rgb reductions, lane-63 rgb/depth stores]
//
// __launch_bounds__(256, 4): VGPR budget 128, not 32 — R4/R5/R6 showed the
// default max-occupancy pressure target makes the scheduler sink any hoisted
// load batch (VGPR_Count pinned at 32-36 across three attempts).
__global__ __launch_bounds__(256, 4) void raymarch_kernel(
    const float* __restrict__ colors,
    const float* __restrict__ dlog,
    const float* __restrict__ depths,
    float* __restrict__ out)
{
    const int wid  = (blockIdx.x * 256 + threadIdx.x) >> 6;   // wave id
    const int lane = threadIdx.x & 63;
    const int ray0 = wid * RPW;

    // ---- issue Phase-A loads (d/g) first, then Phase-B loads (colors) ----
    float2 d[RPW], g[RPW];
    #pragma unroll
    for (int r = 0; r < RPW; ++r) {
        const int ray = ray0 + r;
        d[r] = reinterpret_cast<const float2*>(depths)[(size_t)ray * (Sn / 2) + lane];
        g[r] = reinterpret_cast<const float2*>(dlog)  [(size_t)ray * (Sn / 2) + lane];
    }
    float2 c0[RPW], c1[RPW], c2[RPW];
    #pragma unroll
    for (int r = 0; r < RPW; ++r) {
        const float2* cp = reinterpret_cast<const float2*>(colors)
                         + (size_t)(ray0 + r) * (Sn * 3 / 2);
        c0[r] = cp[lane * 3 + 0];
        c1[r] = cp[lane * 3 + 1];
        c2[r] = cp[lane * 3 + 2];
    }

    // Pin #1: d/g fully retired here (BOTH components -> whole dwordx2 loads,
    // no .y-split). Colors are NOT operands -> they stay outstanding (vmcnt(12)).
    asm volatile(""
        : "+v"(d[0].x), "+v"(d[0].y), "+v"(d[1].x), "+v"(d[1].y),
          "+v"(d[2].x), "+v"(d[2].y), "+v"(d[3].x), "+v"(d[3].y),
          "+v"(g[0].x), "+v"(g[0].y), "+v"(g[1].x), "+v"(g[1].y),
          "+v"(g[2].x), "+v"(g[2].y), "+v"(g[3].x), "+v"(g[3].y));

    const bool valid1 = (lane < 63);   // interval 2*63+1 does not exist

    float w0v[RPW], w1v[RPW], wsumv[RPW], dsumv[RPW];

    // ================= Phase A: geometry/density only =================
    #pragma unroll
    for (int r = 0; r < RPW; ++r) {
        const int ray = ray0 + r;

        // sample 2i+2 lives in lane i+1's first slots: wave_shl:1.
        float d2 = dpp_mov<0x130, 0xF, false>(d[r].x, d[r].x);
        float g2 = dpp_mov<0x130, 0xF, false>(g[r].x, g[r].x);

        float delta0 = d[r].y - d[r].x;
        float dm0    = 0.5f * (d[r].x + d[r].y);
        float x0     = 0.5f * (g[r].x + g[r].y) - 1.0f;
        float delta1 = valid1 ? (d2 - d[r].y)        : 0.0f;
        float dm1    = valid1 ? 0.5f * (d[r].y + d2) : 0.0f;
        float x1     = valid1 ? (0.5f * (g[r].y + g2) - 1.0f) : 0.0f;

        // alpha = 1 - exp(-softplus(x)*delta) = 1 - 2^(-delta * log2(1+e^x))
        float l0 = __log2f(1.0f + __expf(x0));
        float l1 = __log2f(1.0f + __expf(x1));
        l0 = fminf(l0, 1e30f);             // guard inf*0 -> NaN when delta==0
        l1 = fminf(l1, 1e30f);
        float E0 = exp2f(-delta0 * l0);    // = 1 - alpha0
        float E1 = exp2f(-delta1 * l1);
        float alpha0 = 1.0f - E0;
        float alpha1 = 1.0f - E1;          // == 0 for lane 63 (delta1=0)
        float t0 = E0 + EPSF;
        float t1 = valid1 ? (E1 + EPSF) : 1.0f;

        // wave-wide inclusive prefix product (cumprod), all DPP.
        float s  = wave_prefix_prod(t0 * t1);
        float T0 = dpp_mov<0x138, 0xF, false>(1.0f, s);   // exclusive; lane0 -> 1.0
        float T1 = T0 * t0;

        float w0 = (alpha0 + EPSF) * T0;
        float w1 = valid1 ? (alpha1 + EPSF) * T1 : 0.0f;

        // per-interval outputs. ray = 4*wid + r -> ray parity == r parity at
        // compile time: even r -> 8B-aligned -> dwordx2 stores (lanes 0..62).
        const size_t base = (size_t)ray * SI + 2 * lane;
        if ((r & 1) == 0) {
            if (valid1) {
                *reinterpret_cast<float2*>(out + OFF_W     + base) = make_float2(w0, w1);
                *reinterpret_cast<float2*>(out + OFF_WALL  + base) = make_float2(w0, w1);
                *reinterpret_cast<float2*>(out + OFF_ALPHA + base) = make_float2(alpha0, alpha1);
                *reinterpret_cast<float2*>(out + OFF_DMID  + base) = make_float2(dm0, dm1);
            } else {
                out[OFF_W     + base] = w0;
                out[OFF_WALL  + base] = w0;
                out[OFF_ALPHA + base] = alpha0;
                out[OFF_DMID  + base] = dm0;
            }
        } else {
            out[OFF_W     + base] = w0;
            out[OFF_WALL  + base] = w0;
            out[OFF_ALPHA + base] = alpha0;
            out[OFF_DMID  + base] = dm0;
            if (valid1) {
                out[OFF_W     + base + 1] = w1;
                out[OFF_WALL  + base + 1] = w1;
                out[OFF_ALPHA + base + 1] = alpha1;
                out[OFF_DMID  + base + 1] = dm1;
            }
        }

        // color-independent reductions (totals land on lane 63)
        wsumv[r] = wave_sum_last(w0 + w1);
        dsumv[r] = wave_sum_last(w0 * dm0 + w1 * dm1);
        w0v[r] = w0;
        w1v[r] = w1;
    }

    // Pin #2: colors retired here (both components of all 12 loads -> the
    // compiler cannot split/sink any part of them past this point). By now
    // their HBM latency has been hidden under Phase A.
    asm volatile(""
        : "+v"(c0[0].x), "+v"(c0[0].y), "+v"(c0[1].x), "+v"(c0[1].y),
          "+v"(c0[2].x), "+v"(c0[2].y), "+v"(c0[3].x), "+v"(c0[3].y),
          "+v"(c1[0].x), "+v"(c1[0].y), "+v"(c1[1].x), "+v"(c1[1].y),
          "+v"(c1[2].x), "+v"(c1[2].y), "+v"(c1[3].x), "+v"(c1[3].y),
          "+v"(c2[0].x), "+v"(c2[0].y), "+v"(c2[1].x), "+v"(c2[1].y),
          "+v"(c2[2].x), "+v"(c2[2].y), "+v"(c2[3].x), "+v"(c2[3].y));

    // ================= Phase B: color math + composites =================
    #pragma unroll
    for (int r = 0; r < RPW; ++r) {
        const int ray = ray0 + r;

        float cnx = dpp_mov<0x130, 0xF, false>(c0[r].x, c0[r].x);
        float cny = dpp_mov<0x130, 0xF, false>(c0[r].y, c0[r].y);
        float cnz = dpp_mov<0x130, 0xF, false>(c1[r].x, c1[r].x);

        float cm0x = 0.5f * (c0[r].x + c1[r].y);
        float cm0y = 0.5f * (c0[r].y + c2[r].x);
        float cm0z = 0.5f * (c1[r].x + c2[r].y);
        float cm1x = valid1 ? 0.5f * (c1[r].y + cnx) : 0.0f;
        float cm1y = valid1 ? 0.5f * (c2[r].x + cny) : 0.0f;
        float cm1z = valid1 ? 0.5f * (c2[r].y + cnz) : 0.0f;

        float w0 = w0v[r], w1 = w1v[r];
        float rx = wave_sum_last(w0 * cm0x + w1 * cm1x);
        float ry = wave_sum_last(w0 * cm0y + w1 * cm1y);
        float rz = wave_sum_last(w0 * cm0z + w1 * cm1z);

        if (lane == 63) {
            float cd = dsumv[r] / (EPSF + wsumv[r]);
            if (isnan(cd)) cd = 100.0f;              // nan_to_num(nan=MAX_DEPTH)
            cd = fminf(fmaxf(cd, 0.1f), 100.0f);     // clip; also maps ±inf
            out[OFF_RGB + (size_t)ray * 3 + 0] = rx * 2.0f - 1.0f;
            out[OFF_RGB + (size_t)ray * 3 + 1] = ry * 2.0f - 1.0f;
            out[OFF_RGB + (size_t)ray * 3 + 2] = rz * 2.0f - 1.0f;
            out[OFF_DEPTH + ray] = cd;
        }
    }
}

extern "C" void kernel_launch(void* const* d_in, const int* in_sizes, int n_in,
                              void* d_out, int out_size, void* d_ws, size_t ws_size,
                              hipStream_t stream) {
    const float* colors = (const float*)d_in[0];
    const float* dlog   = (const float*)d_in[1];
    const float* depths = (const float*)d_in[2];
    float* out = (float*)d_out;

    dim3 grid(NRAY / (4 * RPW));   // 4 waves per block, RPW rays per wave
    dim3 block(256);
    hipLaunchKernelGGL(raymarch_kernel, grid, block, 0, stream, colors, dlog, depths, out);
}

// Round 8
// 258.845 us; speedup vs baseline: 1.0310x; 1.0084x over previous
//
#include <hip/hip_runtime.h>
#include <math.h>

namespace {
constexpr int Bn = 4, Rn = 16384, Sn = 128;
constexpr int NRAY = Bn * Rn;          // 65536 rays
constexpr int SI   = Sn - 1;           // 127 intervals
constexpr int RPW  = 4;                // rays per wave
// Output layout: tuple concatenated flat in return order
constexpr size_t OFF_RGB   = 0;                                  // [B,R,3]
constexpr size_t OFF_DEPTH = OFF_RGB   + (size_t)NRAY * 3;       // [B,R,1]
constexpr size_t OFF_W     = OFF_DEPTH + (size_t)NRAY;           // [B,R,SI,1]
constexpr size_t OFF_WALL  = OFF_W     + (size_t)NRAY * SI;      // [B,R,SI,1]
constexpr size_t OFF_ALPHA = OFF_WALL  + (size_t)NRAY * SI;      // [B,R,SI,1]
constexpr size_t OFF_DMID  = OFF_ALPHA + (size_t)NRAY * SI;      // [B,R,SI,1]
constexpr float  EPSF      = 1e-10f;
}

// ---- DPP helpers (pure-VALU cross-lane; no LDS/bpermute) ----
template<int CTRL, int ROW_MASK, bool BC>
__device__ __forceinline__ float dpp_mov(float oldv, float src) {
    return __int_as_float(__builtin_amdgcn_update_dpp(
        __float_as_int(oldv), __float_as_int(src), CTRL, ROW_MASK, 0xF, BC));
}

// 64-lane inclusive prefix PRODUCT (GPUOpen scan; bcast row masks REQUIRED).
__device__ __forceinline__ float wave_prefix_prod(float s) {
    s *= dpp_mov<0x111, 0xF, false>(1.0f, s);   // row_shr:1
    s *= dpp_mov<0x112, 0xF, false>(1.0f, s);   // row_shr:2
    s *= dpp_mov<0x114, 0xF, false>(1.0f, s);   // row_shr:4
    s *= dpp_mov<0x118, 0xF, false>(1.0f, s);   // row_shr:8
    s *= dpp_mov<0x142, 0xa, false>(1.0f, s);   // row_bcast:15 -> rows 1,3
    s *= dpp_mov<0x143, 0xc, false>(1.0f, s);   // row_bcast:31 -> rows 2,3
    return s;
}

// 64-lane sum; lane 63 holds the total afterwards.
__device__ __forceinline__ float wave_sum_last(float x) {
    x += dpp_mov<0x111, 0xF, true>(0.0f, x);
    x += dpp_mov<0x112, 0xF, true>(0.0f, x);
    x += dpp_mov<0x114, 0xF, true>(0.0f, x);
    x += dpp_mov<0x118, 0xF, true>(0.0f, x);
    x += dpp_mov<0x142, 0xa, true>(0.0f, x);
    x += dpp_mov<0x143, 0xc, true>(0.0f, x);
    return x;
}

// Inline-asm 8B global load: issue point is pinned at the source position
// (asm volatile blocks are mutually ordered; the scheduler cannot sink,
// split, or re-issue them — defeats the load-sinking seen in R4..R7).
// NOTE: no s_waitcnt inside — the matching wait is a separate asm that
// takes the destination as "+v", creating the use-after-wait dataflow.
__device__ __forceinline__ float2 gload2(const float2* p) {
    float2 r;
    asm volatile("global_load_dwordx2 %0, %1, off" : "=v"(r) : "v"(p));
    return r;
}

// One wave per RPW consecutive rays; lane i owns intervals 2i, 2i+1.
//
// True software pipeline (R8), compiler-proof:
//   [asm-issue 8 d/g loads][asm-issue 12 color loads]     (order = source order)
//   [s_waitcnt vmcnt(12) tied to d/g]   -> d/g retired, colors in flight
//   [Phase A: softplus/scan/weights + w/wall/alpha/dmid stores + wsum/dsum]
//   [s_waitcnt vmcnt(0) tied to colors] -> latency hidden under Phase A
//   [Phase B: color midpoints, rgb reductions, lane-63 rgb/depth stores]
// All vmem preceding wait#1 is exactly the 20 asm loads and d/g are oldest,
// so vmcnt(12) == "oldest 8 retired" (in-order vmcnt retirement).
__global__ __launch_bounds__(256, 4) void raymarch_kernel(
    const float* __restrict__ colors,
    const float* __restrict__ dlog,
    const float* __restrict__ depths,
    float* __restrict__ out)
{
    const int wid  = (blockIdx.x * 256 + threadIdx.x) >> 6;   // wave id
    const int lane = threadIdx.x & 63;
    const int ray0 = wid * RPW;

    const float2* dp = reinterpret_cast<const float2*>(depths) + (size_t)ray0 * (Sn / 2) + lane;
    const float2* gp = reinterpret_cast<const float2*>(dlog)   + (size_t)ray0 * (Sn / 2) + lane;
    const float2* cp = reinterpret_cast<const float2*>(colors) + (size_t)ray0 * (Sn * 3 / 2) + lane * 3;

    float2 d[RPW], g[RPW], c0[RPW], c1[RPW], c2[RPW];
    #pragma unroll
    for (int r = 0; r < RPW; ++r) d[r] = gload2(dp + r * (Sn / 2));
    #pragma unroll
    for (int r = 0; r < RPW; ++r) g[r] = gload2(gp + r * (Sn / 2));
    #pragma unroll
    for (int r = 0; r < RPW; ++r) {
        c0[r] = gload2(cp + r * (Sn * 3 / 2) + 0);
        c1[r] = gload2(cp + r * (Sn * 3 / 2) + 1);
        c2[r] = gload2(cp + r * (Sn * 3 / 2) + 2);
    }

    // Wait #1: oldest 8 (d/g) retired; 12 color loads remain outstanding.
    asm volatile("s_waitcnt vmcnt(12)"
        : "+v"(d[0]), "+v"(d[1]), "+v"(d[2]), "+v"(d[3]),
          "+v"(g[0]), "+v"(g[1]), "+v"(g[2]), "+v"(g[3]));

    const bool valid1 = (lane < 63);   // interval 2*63+1 does not exist

    float w0v[RPW], w1v[RPW], wsumv[RPW], dsumv[RPW];

    // ================= Phase A: geometry/density only =================
    #pragma unroll
    for (int r = 0; r < RPW; ++r) {
        const int ray = ray0 + r;

        // sample 2i+2 lives in lane i+1's first slots: wave_shl:1.
        float d2 = dpp_mov<0x130, 0xF, false>(d[r].x, d[r].x);
        float g2 = dpp_mov<0x130, 0xF, false>(g[r].x, g[r].x);

        float delta0 = d[r].y - d[r].x;
        float dm0    = 0.5f * (d[r].x + d[r].y);
        float x0     = 0.5f * (g[r].x + g[r].y) - 1.0f;
        float delta1 = valid1 ? (d2 - d[r].y)        : 0.0f;
        float dm1    = valid1 ? 0.5f * (d[r].y + d2) : 0.0f;
        float x1     = valid1 ? (0.5f * (g[r].y + g2) - 1.0f) : 0.0f;

        // alpha = 1 - exp(-softplus(x)*delta) = 1 - 2^(-delta * log2(1+e^x))
        float l0 = __log2f(1.0f + __expf(x0));
        float l1 = __log2f(1.0f + __expf(x1));
        l0 = fminf(l0, 1e30f);             // guard inf*0 -> NaN when delta==0
        l1 = fminf(l1, 1e30f);
        float E0 = exp2f(-delta0 * l0);    // = 1 - alpha0
        float E1 = exp2f(-delta1 * l1);
        float alpha0 = 1.0f - E0;
        float alpha1 = 1.0f - E1;          // == 0 for lane 63 (delta1=0)
        float t0 = E0 + EPSF;
        float t1 = valid1 ? (E1 + EPSF) : 1.0f;

        // wave-wide inclusive prefix product (cumprod), all DPP.
        float s  = wave_prefix_prod(t0 * t1);
        float T0 = dpp_mov<0x138, 0xF, false>(1.0f, s);   // exclusive; lane0 -> 1.0
        float T1 = T0 * t0;

        float w0 = (alpha0 + EPSF) * T0;
        float w1 = valid1 ? (alpha1 + EPSF) * T1 : 0.0f;

        // per-interval outputs. ray = 4*wid + r -> ray parity == r parity at
        // compile time: even r -> 8B-aligned -> dwordx2 stores (lanes 0..62).
        const size_t base = (size_t)ray * SI + 2 * lane;
        if ((r & 1) == 0) {
            if (valid1) {
                *reinterpret_cast<float2*>(out + OFF_W     + base) = make_float2(w0, w1);
                *reinterpret_cast<float2*>(out + OFF_WALL  + base) = make_float2(w0, w1);
                *reinterpret_cast<float2*>(out + OFF_ALPHA + base) = make_float2(alpha0, alpha1);
                *reinterpret_cast<float2*>(out + OFF_DMID  + base) = make_float2(dm0, dm1);
            } else {
                out[OFF_W     + base] = w0;
                out[OFF_WALL  + base] = w0;
                out[OFF_ALPHA + base] = alpha0;
                out[OFF_DMID  + base] = dm0;
            }
        } else {
            out[OFF_W     + base] = w0;
            out[OFF_WALL  + base] = w0;
            out[OFF_ALPHA + base] = alpha0;
            out[OFF_DMID  + base] = dm0;
            if (valid1) {
                out[OFF_W     + base + 1] = w1;
                out[OFF_WALL  + base + 1] = w1;
                out[OFF_ALPHA + base + 1] = alpha1;
                out[OFF_DMID  + base + 1] = dm1;
            }
        }

        // color-independent reductions (totals land on lane 63)
        wsumv[r] = wave_sum_last(w0 + w1);
        dsumv[r] = wave_sum_last(w0 * dm0 + w1 * dm1);
        w0v[r] = w0;
        w1v[r] = w1;
    }

    // Wait #2: colors retired (plus any Phase-A stores still outstanding —
    // conservative but correct). Their HBM latency was hidden under Phase A.
    asm volatile("s_waitcnt vmcnt(0)"
        : "+v"(c0[0]), "+v"(c0[1]), "+v"(c0[2]), "+v"(c0[3]),
          "+v"(c1[0]), "+v"(c1[1]), "+v"(c1[2]), "+v"(c1[3]),
          "+v"(c2[0]), "+v"(c2[1]), "+v"(c2[2]), "+v"(c2[3]));

    // ================= Phase B: color math + composites =================
    #pragma unroll
    for (int r = 0; r < RPW; ++r) {
        const int ray = ray0 + r;

        float cnx = dpp_mov<0x130, 0xF, false>(c0[r].x, c0[r].x);
        float cny = dpp_mov<0x130, 0xF, false>(c0[r].y, c0[r].y);
        float cnz = dpp_mov<0x130, 0xF, false>(c1[r].x, c1[r].x);

        float cm0x = 0.5f * (c0[r].x + c1[r].y);
        float cm0y = 0.5f * (c0[r].y + c2[r].x);
        float cm0z = 0.5f * (c1[r].x + c2[r].y);
        float cm1x = valid1 ? 0.5f * (c1[r].y + cnx) : 0.0f;
        float cm1y = valid1 ? 0.5f * (c2[r].x + cny) : 0.0f;
        float cm1z = valid1 ? 0.5f * (c2[r].y + cnz) : 0.0f;

        float w0 = w0v[r], w1 = w1v[r];
        float rx = wave_sum_last(w0 * cm0x + w1 * cm1x);
        float ry = wave_sum_last(w0 * cm0y + w1 * cm1y);
        float rz = wave_sum_last(w0 * cm0z + w1 * cm1z);

        if (lane == 63) {
            float cd = dsumv[r] / (EPSF + wsumv[r]);
            if (isnan(cd)) cd = 100.0f;              // nan_to_num(nan=MAX_DEPTH)
            cd = fminf(fmaxf(cd, 0.1f), 100.0f);     // clip; also maps ±inf
            out[OFF_RGB + (size_t)ray * 3 + 0] = rx * 2.0f - 1.0f;
            out[OFF_RGB + (size_t)ray * 3 + 1] = ry * 2.0f - 1.0f;
            out[OFF_RGB + (size_t)ray * 3 + 2] = rz * 2.0f - 1.0f;
            out[OFF_DEPTH + ray] = cd;
        }
    }
}

extern "C" void kernel_launch(void* const* d_in, const int* in_sizes, int n_in,
                              void* d_out, int out_size, void* d_ws, size_t ws_size,
                              hipStream_t stream) {
    const float* colors = (const float*)d_in[0];
    const float* dlog   = (const float*)d_in[1];
    const float* depths = (const float*)d_in[2];
    float* out = (float*)d_out;

    dim3 grid(NRAY / (4 * RPW));   // 4 waves per block, RPW rays per wave
    dim3 block(256);
    hipLaunchKernelGGL(raymarch_kernel, grid, block, 0, stream, colors, dlog, depths, out);
}